// Round 1
// baseline (1860.742 us; speedup 1.0000x reference)
//
#include <hip/hip_runtime.h>
#include <math.h>

#define NEG_SLOPE 0.2f

// ---- monotonic float<->uint encoding for atomicMax on floats ----
__device__ __forceinline__ unsigned enc_f(float f) {
    unsigned b = __float_as_uint(f);
    return (b & 0x80000000u) ? ~b : (b | 0x80000000u);
}
__device__ __forceinline__ float dec_f(unsigned u) {
    return (u & 0x80000000u) ? __uint_as_float(u ^ 0x80000000u)
                             : __uint_as_float(~u);
}
#define ENC_NEG_INF 0x007FFFFFu  // enc_f(-INFINITY)

// ---- init workspace (poisoned 0xAA every call) ----
__global__ void init_kernel(unsigned* menc, float* ssum, float* acc,
                            float* bnsum, float* bnsq, int nH, int nHC) {
    int i = blockIdx.x * blockDim.x + threadIdx.x;
    int stride = gridDim.x * blockDim.x;
    for (int idx = i; idx < nHC; idx += stride) acc[idx] = 0.f;
    for (int idx = i; idx < nH; idx += stride) { menc[idx] = ENC_NEG_INF; ssum[idx] = 0.f; }
    if (bnsum != nullptr) {
        for (int idx = i; idx < 64; idx += stride) { bnsum[idx] = 0.f; bnsq[idx] = 0.f; }
    }
}

// ---- h = X @ W  (W staged in LDS; fp32 vector ALU — no fp32 MFMA on CDNA4) ----
__global__ void gemm_kernel(const float* __restrict__ X, const float* __restrict__ W,
                            float* __restrict__ Hout, int n, int K, int M) {
    extern __shared__ float Wl[];
    for (int i = threadIdx.x; i < K * M; i += blockDim.x) Wl[i] = W[i];
    __syncthreads();
    int idx = blockIdx.x * blockDim.x + threadIdx.x;
    if (idx >= n * M) return;
    int node = idx / M, col = idx - node * M;
    const float* xr = X + (long)node * K;
    float a = 0.f;
    for (int k = 0; k < K; ++k) a = fmaf(xr[k], Wl[k * M + col], a);
    Hout[idx] = a;
}

// ---- alpha_src/alpha_dst per (node, head) ----
__global__ void alpha_kernel(const float* __restrict__ Hf, const float* __restrict__ a_s,
                             const float* __restrict__ a_d, float* __restrict__ as_o,
                             float* __restrict__ ad_o, int n, int H, int C) {
    int idx = blockIdx.x * blockDim.x + threadIdx.x;
    if (idx >= n * H) return;
    int node = idx / H, h = idx - node * H;
    const float* hr = Hf + (long)node * H * C + h * C;
    float s1 = 0.f, s2 = 0.f;
    for (int c = 0; c < C; ++c) {
        float v = hr[c];
        s1 = fmaf(v, a_s[h * C + c], s1);
        s2 = fmaf(v, a_d[h * C + c], s2);
    }
    as_o[idx] = s1;
    ad_o[idx] = s2;
}

// ---- edge pass A: segment max over dst ----
template <int H>
__global__ void edge_max_kernel(const int* __restrict__ srcs, const int* __restrict__ dsts,
                                int E_, const float* __restrict__ as_,
                                const float* __restrict__ ad_, unsigned* menc, int EA) {
    long idx = (long)blockIdx.x * blockDim.x + threadIdx.x;
    if (idx >= (long)EA * H) return;
    int e = (int)(idx / H), h = (int)(idx - (long)e * H);
    int s, d;
    if (e < E_) { s = srcs[e]; d = dsts[e]; } else { s = d = e - E_; }
    float ev = as_[s * H + h] + ad_[d * H + h];
    ev = ev > 0.f ? ev : NEG_SLOPE * ev;
    atomicMax(&menc[d * H + h], enc_f(ev));
}

// ---- edge pass B+C fused: s[dst,h] += w ; acc[dst,f] += h[src,f]*w ----
template <int C, int HC>
__global__ void edge_acc_kernel(const int* __restrict__ srcs, const int* __restrict__ dsts,
                                int E_, const float* __restrict__ as_,
                                const float* __restrict__ ad_,
                                const unsigned* __restrict__ menc,
                                const float* __restrict__ Hf,
                                float* ssum, float* acc, int EA) {
    constexpr int H = HC / C;
    long idx = (long)blockIdx.x * blockDim.x + threadIdx.x;
    if (idx >= (long)EA * HC) return;
    int e = (int)(idx / HC), f = (int)(idx - (long)e * HC);
    int h = f / C;
    int s, d;
    if (e < E_) { s = srcs[e]; d = dsts[e]; } else { s = d = e - E_; }
    float ev = as_[s * H + h] + ad_[d * H + h];
    ev = ev > 0.f ? ev : NEG_SLOPE * ev;
    float m = dec_f(menc[d * H + h]);
    float w = expf(ev - m);
    if ((f % C) == 0) atomicAdd(&ssum[d * H + h], w);
    atomicAdd(&acc[(long)d * HC + f], Hf[(long)s * HC + f] * w);
}

// ---- finalize (divide by s, +bias) + BN statistics. HC=64, H=4, C=16 fixed. ----
__global__ void finalize_bn_kernel(const float* __restrict__ acc, const float* __restrict__ ssum,
                                   const float* __restrict__ bias, float* __restrict__ feat,
                                   float* bnsum, float* bnsq, int n) {
    __shared__ float ls[256], lq[256];
    int f = threadIdx.x & 63, y = threadIdx.x >> 6;
    int h = f >> 4;  // C = 16
    float ps = 0.f, pq = 0.f;
    for (int node = blockIdx.x * 4 + y; node < n; node += gridDim.x * 4) {
        float v = acc[(long)node * 64 + f] / (ssum[node * 4 + h] + 1e-16f) + bias[f];
        feat[(long)node * 64 + f] = v;
        ps += v;
        pq += v * v;
    }
    ls[threadIdx.x] = ps;
    lq[threadIdx.x] = pq;
    __syncthreads();
    if (y == 0) {
        float a = ls[f] + ls[f + 64] + ls[f + 128] + ls[f + 192];
        float b = lq[f] + lq[f + 64] + lq[f + 128] + lq[f + 192];
        atomicAdd(&bnsum[f], a);
        atomicAdd(&bnsq[f], b);
    }
}

// ---- BN apply + ReLU (HC=64) ----
__global__ void bn_relu_kernel(float* __restrict__ feat, const float* __restrict__ bnsum,
                               const float* __restrict__ bnsq, const float* __restrict__ g,
                               const float* __restrict__ beta, int n) {
    int idx = blockIdx.x * blockDim.x + threadIdx.x;
    if (idx >= n * 64) return;
    int f = idx & 63;
    float inv_n = 1.0f / (float)n;
    float mu = bnsum[f] * inv_n;
    float var = bnsq[f] * inv_n - mu * mu;
    float v = (feat[idx] - mu) * rsqrtf(var + 1e-5f) * g[f] + beta[f];
    feat[idx] = v > 0.f ? v : 0.f;
}

// ---- layer 2 finalize + log_softmax; one wave per node, D=40 ----
__global__ void finalize_lsm_kernel(const float* __restrict__ acc, const float* __restrict__ ssum,
                                    const float* __restrict__ bias, float* __restrict__ out,
                                    int n) {
    int gid = blockIdx.x * blockDim.x + threadIdx.x;
    int node = gid >> 6, lane = gid & 63;
    if (node >= n) return;
    float val = -INFINITY;
    if (lane < 40) val = acc[(long)node * 40 + lane] / (ssum[node] + 1e-16f) + bias[lane];
    float mx = val;
    for (int o = 32; o > 0; o >>= 1) mx = fmaxf(mx, __shfl_xor(mx, o, 64));
    float ex = (lane < 40) ? expf(val - mx) : 0.f;
    float sm = ex;
    for (int o = 32; o > 0; o >>= 1) sm += __shfl_xor(sm, o, 64);
    if (lane < 40) out[(long)node * 40 + lane] = val - mx - logf(sm);
}

static inline int nblk(long total, int b) { return (int)((total + b - 1) / b); }

extern "C" void kernel_launch(void* const* d_in, const int* in_sizes, int n_in,
                              void* d_out, int out_size, void* d_ws, size_t ws_size,
                              hipStream_t stream) {
    const float* x   = (const float*)d_in[0];
    const int*   ei  = (const int*)d_in[1];
    const float* W0  = (const float*)d_in[2];
    const float* as0 = (const float*)d_in[3];
    const float* ad0 = (const float*)d_in[4];
    const float* b0  = (const float*)d_in[5];
    const float* g0  = (const float*)d_in[6];
    const float* be0 = (const float*)d_in[7];
    const float* W1  = (const float*)d_in[8];
    const float* as1 = (const float*)d_in[9];
    const float* ad1 = (const float*)d_in[10];
    const float* b1  = (const float*)d_in[11];
    const float* g1  = (const float*)d_in[12];
    const float* be1 = (const float*)d_in[13];
    const float* W2  = (const float*)d_in[14];
    const float* as2 = (const float*)d_in[15];
    const float* ad2 = (const float*)d_in[16];
    const float* b2  = (const float*)d_in[17];

    const int N  = in_sizes[0] / 128;
    const int E  = in_sizes[1] / 2;
    const int EA = E + N;
    const int* srcs = ei;
    const int* dsts = ei + E;

    float* ws      = (float*)d_ws;
    float* feat    = ws;                        // N*64
    float* h       = feat + (size_t)N * 64;     // N*64
    float* acc     = h + (size_t)N * 64;        // N*64
    float* asrc    = acc + (size_t)N * 64;      // N*4
    float* adst    = asrc + (size_t)N * 4;      // N*4
    float* ssum    = adst + (size_t)N * 4;      // N*4
    unsigned* menc = (unsigned*)(ssum + (size_t)N * 4);  // N*4
    float* bnsum   = (float*)(menc + (size_t)N * 4);     // 64
    float* bnsq    = bnsum + 64;                         // 64

    // ================= layer 0: 128 -> 64 (H=4, C=16) =================
    init_kernel<<<nblk((long)N * 64, 256), 256, 0, stream>>>(menc, ssum, acc, bnsum, bnsq,
                                                             N * 4, N * 64);
    gemm_kernel<<<nblk((long)N * 64, 256), 256, 128 * 64 * 4, stream>>>(x, W0, h, N, 128, 64);
    alpha_kernel<<<nblk((long)N * 4, 256), 256, 0, stream>>>(h, as0, ad0, asrc, adst, N, 4, 16);
    edge_max_kernel<4><<<nblk((long)EA * 4, 256), 256, 0, stream>>>(srcs, dsts, E, asrc, adst,
                                                                    menc, EA);
    edge_acc_kernel<16, 64><<<nblk((long)EA * 64, 256), 256, 0, stream>>>(
        srcs, dsts, E, asrc, adst, menc, h, ssum, acc, EA);
    finalize_bn_kernel<<<512, 256, 0, stream>>>(acc, ssum, b0, feat, bnsum, bnsq, N);
    bn_relu_kernel<<<nblk((long)N * 64, 256), 256, 0, stream>>>(feat, bnsum, bnsq, g0, be0, N);

    // ================= layer 1: 64 -> 64 (H=4, C=16) =================
    init_kernel<<<nblk((long)N * 64, 256), 256, 0, stream>>>(menc, ssum, acc, bnsum, bnsq,
                                                             N * 4, N * 64);
    gemm_kernel<<<nblk((long)N * 64, 256), 256, 64 * 64 * 4, stream>>>(feat, W1, h, N, 64, 64);
    alpha_kernel<<<nblk((long)N * 4, 256), 256, 0, stream>>>(h, as1, ad1, asrc, adst, N, 4, 16);
    edge_max_kernel<4><<<nblk((long)EA * 4, 256), 256, 0, stream>>>(srcs, dsts, E, asrc, adst,
                                                                    menc, EA);
    edge_acc_kernel<16, 64><<<nblk((long)EA * 64, 256), 256, 0, stream>>>(
        srcs, dsts, E, asrc, adst, menc, h, ssum, acc, EA);
    finalize_bn_kernel<<<512, 256, 0, stream>>>(acc, ssum, b1, feat, bnsum, bnsq, N);
    bn_relu_kernel<<<nblk((long)N * 64, 256), 256, 0, stream>>>(feat, bnsum, bnsq, g1, be1, N);

    // ================= layer 2: 64 -> 40 (H=1, C=40) + log_softmax =================
    init_kernel<<<nblk((long)N * 40, 256), 256, 0, stream>>>(menc, ssum, acc, nullptr, nullptr,
                                                             N, N * 40);
    gemm_kernel<<<nblk((long)N * 40, 256), 256, 64 * 40 * 4, stream>>>(feat, W2, h, N, 64, 40);
    alpha_kernel<<<nblk((long)N, 256), 256, 0, stream>>>(h, as2, ad2, asrc, adst, N, 1, 40);
    edge_max_kernel<1><<<nblk((long)EA, 256), 256, 0, stream>>>(srcs, dsts, E, asrc, adst,
                                                                menc, EA);
    edge_acc_kernel<40, 40><<<nblk((long)EA * 40, 256), 256, 0, stream>>>(
        srcs, dsts, E, asrc, adst, menc, h, ssum, acc, EA);
    finalize_lsm_kernel<<<nblk((long)N * 64, 256), 256, 0, stream>>>(acc, ssum, b2,
                                                                     (float*)d_out, N);
}

// Round 3
// 898.237 us; speedup vs baseline: 2.0715x; 2.0715x over previous
//
#include <hip/hip_runtime.h>
#include <math.h>

#define NEG_SLOPE 0.2f

static inline int nblk(long total, int b) { return (int)((total + b - 1) / b); }

// ================= CSR build =================

__global__ void init_deg_kernel(int* degb, float* bnsum, float* bnsq, int n) {
    int i = blockIdx.x * blockDim.x + threadIdx.x;
    if (i < n) degb[i] = 1;  // self-loop
    if (i < 64) { bnsum[i] = 0.f; bnsq[i] = 0.f; }
}

__global__ void hist_kernel(const int* __restrict__ dsts, int* degb, int E_) {
    int e = blockIdx.x * blockDim.x + threadIdx.x;
    if (e < E_) atomicAdd(&degb[dsts[e]], 1);
}

// partial[b] = sum of degb over chunk b (chunk = 256)
__global__ void scan_part_kernel(const int* __restrict__ degb, int* partial, int n) {
    __shared__ int sd[256];
    int t = threadIdx.x;
    int i = blockIdx.x * 256 + t;
    sd[t] = (i < n) ? degb[i] : 0;
    __syncthreads();
    for (int o = 128; o > 0; o >>= 1) {
        if (t < o) sd[t] += sd[t + o];
        __syncthreads();
    }
    if (t == 0) partial[blockIdx.x] = sd[0];
}

// exclusive scan of partial[0..255] in place (single block)
__global__ void scan_top_kernel(int* partial, int P) {
    __shared__ int sd[256];
    int t = threadIdx.x;
    int v = (t < P) ? partial[t] : 0;
    sd[t] = v;
    __syncthreads();
    for (int o = 1; o < 256; o <<= 1) {
        int x = (t >= o) ? sd[t - o] : 0;
        __syncthreads();
        sd[t] += x;
        __syncthreads();
    }
    if (t < P) partial[t] = sd[t] - v;  // exclusive
}

// offs[i] = chunk-base + exclusive-scan-within-chunk; rowend = cursor init
__global__ void scan_chunk_kernel(const int* __restrict__ degb, const int* __restrict__ partial,
                                  int* offs, int* rowend, int n) {
    __shared__ int sd[256];
    int t = threadIdx.x;
    int i = blockIdx.x * 256 + t;
    int v = (i < n) ? degb[i] : 0;
    sd[t] = v;
    __syncthreads();
    for (int o = 1; o < 256; o <<= 1) {
        int x = (t >= o) ? sd[t - o] : 0;
        __syncthreads();
        sd[t] += x;
        __syncthreads();
    }
    if (i < n) {
        int off = partial[blockIdx.x] + sd[t] - v;
        offs[i] = off;
        rowend[i] = off;  // cursor; becomes row_end after scatter
    }
}

__global__ void scatter_kernel(const int* __restrict__ srcs, const int* __restrict__ dsts,
                               int E_, int* rowend, int* esrc, int EA) {
    int i = blockIdx.x * blockDim.x + threadIdx.x;
    if (i >= EA) return;
    int s, d;
    if (i < E_) { s = srcs[i]; d = dsts[i]; } else { s = d = i - E_; }
    int pos = atomicAdd(&rowend[d], 1);
    esrc[pos] = s;
}

// ================= dense small ops =================

// h = X @ W (W staged in LDS; fp32 vector ALU — no fp32 MFMA on CDNA4)
__global__ void gemm_kernel(const float* __restrict__ X, const float* __restrict__ W,
                            float* __restrict__ Hout, int n, int K, int M) {
    extern __shared__ float Wl[];
    for (int i = threadIdx.x; i < K * M; i += blockDim.x) Wl[i] = W[i];
    __syncthreads();
    int idx = blockIdx.x * blockDim.x + threadIdx.x;
    if (idx >= n * M) return;
    int node = idx / M, col = idx - node * M;
    const float* xr = X + (long)node * K;
    float a = 0.f;
    for (int k = 0; k < K; ++k) a = fmaf(xr[k], Wl[k * M + col], a);
    Hout[idx] = a;
}

__global__ void alpha_kernel(const float* __restrict__ Hf, const float* __restrict__ a_s,
                             const float* __restrict__ a_d, float* __restrict__ as_o,
                             float* __restrict__ ad_o, int n, int H, int C) {
    int idx = blockIdx.x * blockDim.x + threadIdx.x;
    if (idx >= n * H) return;
    int node = idx / H, h = idx - node * H;
    const float* hr = Hf + (long)node * H * C + h * C;
    float s1 = 0.f, s2 = 0.f;
    for (int c = 0; c < C; ++c) {
        float v = hr[c];
        s1 = fmaf(v, a_s[h * C + c], s1);
        s2 = fmaf(v, a_d[h * C + c], s2);
    }
    as_o[idx] = s1;
    ad_o[idx] = s2;
}

// ================= node-centric gather (no atomics) =================

// Layers 0/1: H=4, C=16, HC=64. One wave per dst node; lane = output feature.
__global__ void gather64_kernel(const int* __restrict__ offs, const int* __restrict__ rowend,
                                const int* __restrict__ esrc, const float* __restrict__ as_,
                                const float* __restrict__ ad_, const float* __restrict__ Hf,
                                const float* __restrict__ bias, float* __restrict__ feat,
                                int n) {
    int node = blockIdx.x * (blockDim.x >> 6) + (threadIdx.x >> 6);
    if (node >= n) return;
    int lane = threadIdx.x & 63;
    int h = lane >> 4;
    int start = offs[node], end = rowend[node];

    float4 adv = *(const float4*)(ad_ + (long)node * 4);

    // pass 1: per-head max, lane-parallel over edges
    float mx0 = -1e30f, mx1 = -1e30f, mx2 = -1e30f, mx3 = -1e30f;
    for (int i = start + lane; i < end; i += 64) {
        int s = esrc[i];
        float4 av = *(const float4*)(as_ + (long)s * 4);
        float e0 = av.x + adv.x; e0 = e0 > 0.f ? e0 : NEG_SLOPE * e0;
        float e1 = av.y + adv.y; e1 = e1 > 0.f ? e1 : NEG_SLOPE * e1;
        float e2 = av.z + adv.z; e2 = e2 > 0.f ? e2 : NEG_SLOPE * e2;
        float e3 = av.w + adv.w; e3 = e3 > 0.f ? e3 : NEG_SLOPE * e3;
        mx0 = fmaxf(mx0, e0); mx1 = fmaxf(mx1, e1);
        mx2 = fmaxf(mx2, e2); mx3 = fmaxf(mx3, e3);
    }
#pragma unroll
    for (int o = 32; o > 0; o >>= 1) {
        mx0 = fmaxf(mx0, __shfl_xor(mx0, o, 64));
        mx1 = fmaxf(mx1, __shfl_xor(mx1, o, 64));
        mx2 = fmaxf(mx2, __shfl_xor(mx2, o, 64));
        mx3 = fmaxf(mx3, __shfl_xor(mx3, o, 64));
    }
    float mh  = (h == 0) ? mx0 : (h == 1) ? mx1 : (h == 2) ? mx2 : mx3;
    float adh = (h == 0) ? adv.x : (h == 1) ? adv.y : (h == 2) ? adv.z : adv.w;

    // pass 2: feature-parallel; wave walks edges serially, registers accumulate
    float acc = 0.f, wsum = 0.f;
#pragma unroll 4
    for (int i = start; i < end; ++i) {
        int s = esrc[i];
        float ev = as_[(long)s * 4 + h] + adh;
        ev = ev > 0.f ? ev : NEG_SLOPE * ev;
        float w = __expf(ev - mh);
        acc = fmaf(Hf[(long)s * 64 + lane], w, acc);
        wsum += w;
    }
    feat[(long)node * 64 + lane] = acc / (wsum + 1e-16f) + bias[lane];
}

// Layer 2: H=1, C=40, fused log_softmax epilogue. One wave per dst node.
__global__ void gather40_lsm_kernel(const int* __restrict__ offs, const int* __restrict__ rowend,
                                    const int* __restrict__ esrc, const float* __restrict__ as_,
                                    const float* __restrict__ ad_, const float* __restrict__ Hf,
                                    const float* __restrict__ bias, float* __restrict__ out,
                                    int n) {
    int node = blockIdx.x * (blockDim.x >> 6) + (threadIdx.x >> 6);
    if (node >= n) return;
    int lane = threadIdx.x & 63;
    int start = offs[node], end = rowend[node];
    float adv = ad_[node];

    float mx = -1e30f;
    for (int i = start + lane; i < end; i += 64) {
        int s = esrc[i];
        float e = as_[s] + adv;
        e = e > 0.f ? e : NEG_SLOPE * e;
        mx = fmaxf(mx, e);
    }
#pragma unroll
    for (int o = 32; o > 0; o >>= 1) mx = fmaxf(mx, __shfl_xor(mx, o, 64));

    float acc = 0.f, wsum = 0.f;
#pragma unroll 4
    for (int i = start; i < end; ++i) {
        int s = esrc[i];
        float ev = as_[s] + adv;
        ev = ev > 0.f ? ev : NEG_SLOPE * ev;
        float w = __expf(ev - mx);
        wsum += w;
        if (lane < 40) acc = fmaf(Hf[(long)s * 40 + lane], w, acc);
    }
    float val = (lane < 40) ? acc / (wsum + 1e-16f) + bias[lane] : -1e30f;

    float m2 = val;
#pragma unroll
    for (int o = 32; o > 0; o >>= 1) m2 = fmaxf(m2, __shfl_xor(m2, o, 64));
    float ex = (lane < 40) ? __expf(val - m2) : 0.f;
#pragma unroll
    for (int o = 32; o > 0; o >>= 1) ex += __shfl_xor(ex, o, 64);
    if (lane < 40) out[(long)node * 40 + lane] = val - m2 - logf(ex);
}

// ================= BN =================

__global__ void zero_bn_kernel(float* bnsum, float* bnsq) {
    int i = threadIdx.x;
    if (i < 64) { bnsum[i] = 0.f; bnsq[i] = 0.f; }
}

__global__ void bn_stats_kernel(const float* __restrict__ feat, float* bnsum, float* bnsq,
                                int n) {
    __shared__ float ls[256], lq[256];
    int f = threadIdx.x & 63, y = threadIdx.x >> 6;
    float ps = 0.f, pq = 0.f;
    for (int node = blockIdx.x * 4 + y; node < n; node += gridDim.x * 4) {
        float v = feat[(long)node * 64 + f];
        ps += v;
        pq += v * v;
    }
    ls[threadIdx.x] = ps;
    lq[threadIdx.x] = pq;
    __syncthreads();
    if (y == 0) {
        atomicAdd(&bnsum[f], ls[f] + ls[f + 64] + ls[f + 128] + ls[f + 192]);
        atomicAdd(&bnsq[f], lq[f] + lq[f + 64] + lq[f + 128] + lq[f + 192]);
    }
}

__global__ void bn_relu_kernel(float* __restrict__ feat, const float* __restrict__ bnsum,
                               const float* __restrict__ bnsq, const float* __restrict__ g,
                               const float* __restrict__ beta, int n) {
    int idx = blockIdx.x * blockDim.x + threadIdx.x;
    if (idx >= n * 64) return;
    int f = idx & 63;
    float inv_n = 1.0f / (float)n;
    float mu = bnsum[f] * inv_n;
    float var = bnsq[f] * inv_n - mu * mu;
    float v = (feat[idx] - mu) * rsqrtf(var + 1e-5f) * g[f] + beta[f];
    feat[idx] = v > 0.f ? v : 0.f;
}

// ================= launch =================

extern "C" void kernel_launch(void* const* d_in, const int* in_sizes, int n_in,
                              void* d_out, int out_size, void* d_ws, size_t ws_size,
                              hipStream_t stream) {
    const float* x   = (const float*)d_in[0];
    const int*   ei  = (const int*)d_in[1];
    const float* W0  = (const float*)d_in[2];
    const float* as0 = (const float*)d_in[3];
    const float* ad0 = (const float*)d_in[4];
    const float* b0  = (const float*)d_in[5];
    const float* g0  = (const float*)d_in[6];
    const float* be0 = (const float*)d_in[7];
    const float* W1  = (const float*)d_in[8];
    const float* as1 = (const float*)d_in[9];
    const float* ad1 = (const float*)d_in[10];
    const float* b1  = (const float*)d_in[11];
    const float* g1  = (const float*)d_in[12];
    const float* be1 = (const float*)d_in[13];
    const float* W2  = (const float*)d_in[14];
    const float* as2 = (const float*)d_in[15];
    const float* ad2 = (const float*)d_in[16];
    const float* b2  = (const float*)d_in[17];

    const int N  = in_sizes[0] / 128;
    const int E  = in_sizes[1] / 2;
    const int EA = E + N;
    const int* srcs = ei;
    const int* dsts = ei + E;

    float* ws    = (float*)d_ws;
    float* feat  = ws;                         // N*64
    float* h     = feat + (size_t)N * 64;      // N*64
    float* asrc  = h + (size_t)N * 64;         // N*4
    float* adst  = asrc + (size_t)N * 4;       // N*4
    float* bnsum = adst + (size_t)N * 4;       // 64
    float* bnsq  = bnsum + 64;                 // 64
    int* offs    = (int*)(bnsq + 64);          // N
    int* rowend  = offs + N;                   // N (cursor -> row_end)
    int* degb    = rowend + N;                 // N
    int* partial = degb + N;                   // 256
    int* esrc    = partial + 256;              // EA

    const int nchunk = (N + 255) / 256;  // 196 <= 256

    // ---- CSR build (once per call) ----
    init_deg_kernel<<<nblk(N, 256), 256, 0, stream>>>(degb, bnsum, bnsq, N);
    hist_kernel<<<nblk(E, 256), 256, 0, stream>>>(dsts, degb, E);
    scan_part_kernel<<<nchunk, 256, 0, stream>>>(degb, partial, N);
    scan_top_kernel<<<1, 256, 0, stream>>>(partial, nchunk);
    scan_chunk_kernel<<<nchunk, 256, 0, stream>>>(degb, partial, offs, rowend, N);
    scatter_kernel<<<nblk(EA, 256), 256, 0, stream>>>(srcs, dsts, E, rowend, esrc, EA);

    // ---- layer 0: 128 -> 64 (H=4, C=16) ----
    gemm_kernel<<<nblk((long)N * 64, 256), 256, 128 * 64 * 4, stream>>>(x, W0, h, N, 128, 64);
    alpha_kernel<<<nblk((long)N * 4, 256), 256, 0, stream>>>(h, as0, ad0, asrc, adst, N, 4, 16);
    gather64_kernel<<<nblk(N, 4), 256, 0, stream>>>(offs, rowend, esrc, asrc, adst, h, b0,
                                                    feat, N);
    bn_stats_kernel<<<512, 256, 0, stream>>>(feat, bnsum, bnsq, N);
    bn_relu_kernel<<<nblk((long)N * 64, 256), 256, 0, stream>>>(feat, bnsum, bnsq, g0, be0, N);

    // ---- layer 1: 64 -> 64 (H=4, C=16) ----
    zero_bn_kernel<<<1, 128, 0, stream>>>(bnsum, bnsq);
    gemm_kernel<<<nblk((long)N * 64, 256), 256, 64 * 64 * 4, stream>>>(feat, W1, h, N, 64, 64);
    alpha_kernel<<<nblk((long)N * 4, 256), 256, 0, stream>>>(h, as1, ad1, asrc, adst, N, 4, 16);
    gather64_kernel<<<nblk(N, 4), 256, 0, stream>>>(offs, rowend, esrc, asrc, adst, h, b1,
                                                    feat, N);
    bn_stats_kernel<<<512, 256, 0, stream>>>(feat, bnsum, bnsq, N);
    bn_relu_kernel<<<nblk((long)N * 64, 256), 256, 0, stream>>>(feat, bnsum, bnsq, g1, be1, N);

    // ---- layer 2: 64 -> 40 (H=1, C=40) + log_softmax ----
    gemm_kernel<<<nblk((long)N * 40, 256), 256, 64 * 40 * 4, stream>>>(feat, W2, h, N, 64, 40);
    alpha_kernel<<<nblk((long)N, 256), 256, 0, stream>>>(h, as2, ad2, asrc, adst, N, 1, 40);
    gather40_lsm_kernel<<<nblk(N, 4), 256, 0, stream>>>(offs, rowend, esrc, asrc, adst, h, b2,
                                                        (float*)d_out, N);
}